// Round 5
// baseline (314.472 us; speedup 1.0000x reference)
//
#include <hip/hip_runtime.h>
#include <math.h>
#include <float.h>

// AFM forward: B=4096, F=39, V=100000, E=16, A=16, P=741
// out[b] = bias + sum_f emb1[f,idx]*xv + (sum_p softmax(s)_p * q_p)
//   s_p = wij . (W1@H)   (b1.H constant over pairs -> cancels in softmax)
//   q_p = wij . Pv,  wij = (e_i*xv_i) o (e_j*xv_j)
// One wave (64 lanes) per batch row; 12 contiguous pairs per lane with
// register-cached i-row (ui = si o WH, ri = si o Pv). Online softmax
// (running m/den/num). mx starts at -FLT_MAX (not -inf) so the cross-lane
// merge can never produce (-inf)-(-inf)=NaN regardless of reduce order.

#define BB 4096
#define FF 39
#define VV 100000
#define EE 16
#define PP 741
#define SS 20   /* LDS row stride in floats: 80B, 16B-aligned, not pow2 */

__global__ __launch_bounds__(64) void afm_kernel(
    const int* __restrict__ Xi, const float* __restrict__ Xv,
    const float* __restrict__ emb1, const float* __restrict__ emb2,
    const float* __restrict__ W1, const float* __restrict__ H,
    const float* __restrict__ Pv, const float* __restrict__ bias,
    float* __restrict__ out)
{
    __shared__ float sec[FF * SS];

    const int b = blockIdx.x;
    const int l = threadIdx.x;

    // ---- per-lane field loads (lane f owns field f), issue gathers early ----
    int   xi = 0;
    float xv = 0.f, fo = 0.f;
    if (l < FF) {
        xi = Xi[b * FF + l];
        xv = Xv[b * FF + l];
        fo = emb1[(long)l * VV + xi] * xv;   // first-order contribution
    }

    // ---- fold WH[e] = sum_a W1[e][a]*H[a]; lane computes e = l&15, broadcast ----
    const int e = l & 15;
    float whe = 0.f;
    {
        const float4* __restrict__ W1r = reinterpret_cast<const float4*>(W1 + e * 16);
        const float4* __restrict__ H4  = reinterpret_cast<const float4*>(H);
#pragma unroll
        for (int m = 0; m < 4; ++m) {
            const float4 w = W1r[m], h = H4[m];
            whe += w.x * h.x + w.y * h.y + w.z * h.z + w.w * h.w;
        }
    }
    float wh[16];
#pragma unroll
    for (int k = 0; k < 16; ++k) wh[k] = __shfl(whe, k, 64);
    float pv[16];
    {
        const float4* __restrict__ Pv4 = reinterpret_cast<const float4*>(Pv);
#pragma unroll
        for (int m = 0; m < 4; ++m) {
            const float4 v = Pv4[m];
            pv[m * 4 + 0] = v.x; pv[m * 4 + 1] = v.y;
            pv[m * 4 + 2] = v.z; pv[m * 4 + 3] = v.w;
        }
    }

    // ---- gather second-order rows into LDS: (f,e4) per lane-slot, 3 rounds ----
#pragma unroll
    for (int k = 0; k < 3; ++k) {
        const int t = l + 64 * k;
        if (t < FF * 4) {
            const int f = t >> 2, e4 = t & 3;
            const int   idxf = __shfl(xi, f, 64);
            const float xvf  = __shfl(xv, f, 64);
            float4 v = *reinterpret_cast<const float4*>(
                emb2 + ((long)f * VV + idxf) * EE + e4 * 4);
            v.x *= xvf; v.y *= xvf; v.z *= xvf; v.w *= xvf;
            *reinterpret_cast<float4*>(&sec[f * SS + e4 * 4]) = v;
        }
    }
    __syncthreads();   // single-wave block: orders LDS writes -> reads

    // ---- pair phase: 12 contiguous pairs per lane, register-cached i-row ----
    const int p0  = l * 12;
    const int cnt = (PP - p0 < 0) ? 0 : ((PP - p0 < 12) ? (PP - p0) : 12);
    int rem = (p0 < PP) ? p0 : (PP - 1);
    int i = 0;
    while (rem >= FF - 1 - i) { rem -= FF - 1 - i; ++i; }
    int j = i + 1 + rem;

    float ui[16], ri[16];
    auto load_i = [&](int ii) {
#pragma unroll
        for (int m = 0; m < 4; ++m) {
            const float4 s4 = *reinterpret_cast<const float4*>(&sec[ii * SS + m * 4]);
            ui[m * 4 + 0] = s4.x * wh[m * 4 + 0]; ri[m * 4 + 0] = s4.x * pv[m * 4 + 0];
            ui[m * 4 + 1] = s4.y * wh[m * 4 + 1]; ri[m * 4 + 1] = s4.y * pv[m * 4 + 1];
            ui[m * 4 + 2] = s4.z * wh[m * 4 + 2]; ri[m * 4 + 2] = s4.z * pv[m * 4 + 2];
            ui[m * 4 + 3] = s4.w * wh[m * 4 + 3]; ri[m * 4 + 3] = s4.w * pv[m * 4 + 3];
        }
    };
    load_i(i);

    // ---- online softmax accumulation (running max / den / num) ----
    float mx = -FLT_MAX, den = 0.f, num = 0.f;
#pragma unroll
    for (int k = 0; k < 12; ++k) {
        if (k < cnt) {
            float s = 0.f, q = 0.f;
#pragma unroll
            for (int m = 0; m < 4; ++m) {
                const float4 s4 = *reinterpret_cast<const float4*>(&sec[j * SS + m * 4]);
                s += ui[m * 4 + 0] * s4.x + ui[m * 4 + 1] * s4.y
                   + ui[m * 4 + 2] * s4.z + ui[m * 4 + 3] * s4.w;
                q += ri[m * 4 + 0] * s4.x + ri[m * 4 + 1] * s4.y
                   + ri[m * 4 + 2] * s4.z + ri[m * 4 + 3] * s4.w;
            }
            if (s > mx) {                    // rescale on new max
                const float sc = __expf(mx - s);   // saturates to 0 first time
                den *= sc; num *= sc; mx = s;
            }
            const float ex = __expf(s - mx);
            den += ex;
            num += ex * q;
            if (++j == FF) {                 // advance to next i-row
                ++i; j = i + 1;
                if (k + 1 < cnt) load_i(i);
            }
        }
    }

    // ---- cross-lane merge of (mx, den, num) + first-order sum ----
    // mx >= -FLT_MAX always, so mx - mn is never NaN; empty lanes contribute
    // den=num=0 regardless of their scale factor.
#pragma unroll
    for (int o = 32; o; o >>= 1) {
        const float mo = __shfl_xor(mx,  o, 64);
        const float dl = __shfl_xor(den, o, 64);
        const float nl = __shfl_xor(num, o, 64);
        const float mn = fmaxf(mx, mo);
        const float sa = __expf(mx - mn);
        const float sb = __expf(mo - mn);
        den = den * sa + dl * sb;
        num = num * sa + nl * sb;
        mx  = mn;
        fo += __shfl_xor(fo, o, 64);
    }
    if (l == 0) out[b] = bias[0] + fo + num / den;
}

extern "C" void kernel_launch(void* const* d_in, const int* in_sizes, int n_in,
                              void* d_out, int out_size, void* d_ws, size_t ws_size,
                              hipStream_t stream)
{
    const int*   Xi   = (const int*)d_in[0];
    const float* Xv   = (const float*)d_in[1];
    const float* emb1 = (const float*)d_in[2];
    const float* emb2 = (const float*)d_in[3];
    const float* W1   = (const float*)d_in[4];
    // d_in[5] = b1 (cancels in softmax; unused)
    const float* H    = (const float*)d_in[6];
    const float* Pv   = (const float*)d_in[7];
    const float* bias = (const float*)d_in[8];
    (void)in_sizes; (void)n_in; (void)out_size; (void)d_ws; (void)ws_size;

    afm_kernel<<<BB, 64, 0, stream>>>(Xi, Xv, emb1, emb2, W1, H, Pv, bias,
                                      (float*)d_out);
}